// Round 6
// baseline (188.333 us; speedup 1.0000x reference)
//
#include <hip/hip_runtime.h>
#include <hip/hip_bf16.h>
#include <stdint.h>

typedef __attribute__((ext_vector_type(8))) short short8;
typedef __attribute__((ext_vector_type(4))) float f32x4;
typedef __attribute__((ext_vector_type(4))) unsigned int u32x4;
typedef __attribute__((ext_vector_type(2))) unsigned int u32x2;

// Skeleton (fixed in reference) — constexpr so fully-unrolled loops fold
// every index/degree/offset into immediates.
constexpr int kNBR[17][4] = {
    {7, 1, 4, 0}, {0, 2, 0, 0}, {1, 3, 0, 0}, {2, 0, 0, 0},
    {0, 5, 0, 0}, {4, 6, 0, 0}, {5, 0, 0, 0}, {0, 8, 0, 0},
    {7, 9, 11, 14}, {8, 10, 0, 0}, {9, 0, 0, 0}, {8, 12, 0, 0},
    {11, 13, 0, 0}, {12, 0, 0, 0}, {8, 15, 0, 0}, {14, 16, 0, 0},
    {15, 0, 0, 0}};
constexpr int kDEG[17] = {3,2,2,1,2,2,1,2,4,2,1,2,2,1,2,2,1};
constexpr float kRDEG[5] = {0.f, 1.f, 0.5f, 0.33333334f, 0.25f};

__device__ inline unsigned short f2bf(float f) {
  union { float f; uint32_t u; } v; v.f = f;
  uint32_t u = v.u;
  uint32_t r = u + 0x7fffu + ((u >> 16) & 1u);  // RNE
  return (unsigned short)(r >> 16);
}
// hardware v_cvt_pk_bf16_f32 (RNE), a in low 16, b in high 16
__device__ inline uint32_t pk2(float a, float b) {
  union { __hip_bfloat162 h; uint32_t u; } v;
  v.h = __float22bfloat162_rn(make_float2(a, b));
  return v.u;
}
__device__ inline f32x4 mfma16(short8 a, short8 b, f32x4 c) {
  return __builtin_amdgcn_mfma_f32_16x16x32_bf16(a, b, c, 0, 0, 0);
}
__device__ inline int hswz(int row, int cb) {
  return row * 128 + (cb ^ ((row & 7) << 4));
}

// ---------------- prep kernel (unchanged from R5) ----------------
__global__ void prep(const float* __restrict__ W1,
                     const float* __restrict__ W2,
                     const float* __restrict__ Wp2,
                     const float* __restrict__ W3,
                     const float* __restrict__ Wp1,
                     const float* __restrict__ b3,
                     const float* __restrict__ bp1,
                     const float* __restrict__ b1,
                     short* __restrict__ W1b,
                     short* __restrict__ W2b,
                     short* __restrict__ Wp2b,
                     short* __restrict__ Mb,
                     float* __restrict__ bp1p) {
  __shared__ float w3s[4096];
  __shared__ float Qs[256];
  const int tid = threadIdx.x;
  const int bx = blockIdx.x;
  if (bx < 272) {
    for (int q = tid; q < 4096; q += 256) w3s[q] = W3[q];
    {
      int ro = tid >> 6, k = tid & 63;
      int r = bx * 4 + ro;
      int f = r / 17, i = r - f * 17;
      int dj = kDEG[i];
      float s = 0.f;
#pragma unroll
      for (int t = 0; t < 4; t++) {
        if (t < dj) {
          int nb = kNBR[i][t];
          s += kRDEG[kDEG[nb]] * Wp1[f * 1088 + nb * 64 + k];
        }
      }
      Qs[ro * 64 + k] = s;
    }
    __syncthreads();
    {
      int ro = tid >> 6, c = tid & 63;
      int r = bx * 4 + ro;
      int f = r / 17, i = r - f * 17;
      float s = 0.f;
#pragma unroll
      for (int k = 0; k < 64; k++) s += Qs[ro * 64 + k] * w3s[k * 64 + c];
      int col = i * 64 + c;
      int kk = col >> 5, qq = (col >> 3) & 3, cb = col & 7;
      int w = f >> 4, l15 = f & 15;
      Mb[(((w * 34 + kk) * 64) + qq * 16 + l15) * 8 + cb] = (short)f2bf(s);
    }
  } else if (bx < 354) {
    int q = (bx - 272) * 256 + tid;
    if (q < 4096) W2b[q] = (short)f2bf(W2[q]);
    int q2 = q - 4096;
    if (q2 >= 0 && q2 < 16384) Wp2b[q2] = (short)f2bf(Wp2[q2]);
    int q3 = q - 20480;
    if (q3 >= 0 && q3 < 512) {
      int k = q3 & 7, row = q3 >> 3;
      short v = 0;
      if (k < 3) v = (short)f2bf(W1[row * 3 + k]);
      else if (k == 3) v = (short)f2bf(b1[row]);  // bias in spare K-slot
      W1b[q3] = v;
    }
  } else {
    int wv = tid >> 6, l = tid & 63;
    int f = (bx - 354) * 4 + wv;
    float s = 0.f;
#pragma unroll
    for (int i = 0; i < 17; i++) s += Wp1[f * 1088 + i * 64 + l] * b3[l];
#pragma unroll
    for (int off = 32; off > 0; off >>= 1) s += __shfl_down(s, off);
    if (l == 0) bp1p[f] = bp1[f] + s;
  }
}

// ---------------- main fused kernel: barrier-free, wave-autonomous ----------------
// One 64-thread (single-wave) workgroup owns 16 elements END-TO-END: all 17
// joints of L1/L2, the pool, and pool2. All producer->consumer LDS traffic is
// intra-wave; the per-wave in-order DS pipeline provides ordering, so the
// kernel has ZERO __syncthreads (R5 had 6 block-wide barrier+drains, the
// dominant stall per the 49% issue-utilization analysis). Waves are perfectly
// balanced (identical work). LDS/block = 34816 (hbuf) + 3264 (xs, zb overlay)
// = 38080 B -> 4 single-wave blocks/CU with fine-grained turnover.
// launch_bounds(64,1) -> up to 512 VGPR: all 17 joints' packed h2 (136 VGPR)
// stay in registers across the in-wave WAR point; Mb pool stream prefetched
// 24 fragments deep to cover L2 latency at 1 wave/SIMD.
__launch_bounds__(64, 1)
__global__ void gcn_main(const float* __restrict__ X,
                         const short* __restrict__ Mb,
                         const short* __restrict__ Wp2b,
                         const short* __restrict__ W2b,
                         const short* __restrict__ W1b,
                         const float* __restrict__ bp1p,
                         const float* __restrict__ b2g,
                         const float* __restrict__ bp2g,
                         float* __restrict__ OUT) {
  __shared__ __align__(16) short hbuf[17408];  // 34816 B (h1 -> h2 in place)
  __shared__ __align__(16) float xs[816];      // 3264 B; zb overlays after L1
  const int lane = threadIdx.x;                // 64-thread block = one wave
  const int ln15 = lane & 15;
  const int quad = lane >> 4;
  const int e0 = blockIdx.x * 16;
  char* hb = (char*)hbuf;

  // ---- stage X (wave-private; in-order DS pipeline, no barrier) ----
  {
    const f32x4* src = (const f32x4*)(X + (size_t)e0 * 51);
    f32x4* dst = (f32x4*)xs;
    dst[lane] = src[lane];
    dst[lane + 64] = src[lane + 64];
    dst[lane + 128] = src[lane + 128];
    if (lane < 12) dst[lane + 192] = src[lane + 192];
  }
  // ---- weight fragments / biases straight to registers (L2-cached) ----
  short8 w1f[4];
#pragma unroll
  for (int ft = 0; ft < 4; ft++)
    w1f[ft] = *(const short8*)(W1b + (ft * 16 + ln15) * 8);
  short8 w2f[2][4];
#pragma unroll
  for (int kk = 0; kk < 2; kk++)
#pragma unroll
    for (int ft = 0; ft < 4; ft++)
      w2f[kk][ft] = *(const short8*)(W2b + (ft * 16 + ln15) * 64 + kk * 32 + quad * 8);
  f32x4 bv2[4];
#pragma unroll
  for (int ft = 0; ft < 4; ft++)
    bv2[ft] = *(const f32x4*)(b2g + ft * 16 + quad * 4);

  // ---- Layer 1, all 17 joints (fused agg0; b1 via K-slot; relu+pack) ----
#pragma unroll
  for (int j = 0; j < 17; j++) {
    const int dj = kDEG[j];
    const float w = kRDEG[dj];
    union { short8 s; u32x4 u; } fr;
    fr.u = (u32x4){0u, 0u, 0u, 0u};
    if (quad == 0) {
      float s0, s1, s2;
      {
        int b = ln15 * 51 + kNBR[j][0] * 3;
        s0 = xs[b]; s1 = xs[b + 1]; s2 = xs[b + 2];
      }
      if (dj > 1) {
        int b = ln15 * 51 + kNBR[j][1] * 3;
        s0 += xs[b]; s1 += xs[b + 1]; s2 += xs[b + 2];
      }
      if (dj > 2) {
        int b = ln15 * 51 + kNBR[j][2] * 3;
        s0 += xs[b]; s1 += xs[b + 1]; s2 += xs[b + 2];
      }
      if (dj > 3) {
        int b = ln15 * 51 + kNBR[j][3] * 3;
        s0 += xs[b]; s1 += xs[b + 1]; s2 += xs[b + 2];
      }
      fr.u.x = pk2(s0 * w, s1 * w);
      fr.u.y = pk2(s2 * w, 1.0f);  // k=3 = 1.0 activates bias row of W1b
    }
    f32x4 a[4];
#pragma unroll
    for (int ft = 0; ft < 4; ft++)
      a[ft] = mfma16(w1f[ft], fr.s, (f32x4){0.f, 0.f, 0.f, 0.f});
#pragma unroll
    for (int ft = 0; ft < 4; ft++) {
      int fb = ft * 16 + quad * 4;
      u32x2 pk;
      pk.x = pk2(fmaxf(a[ft].x, 0.f), fmaxf(a[ft].y, 0.f));
      pk.y = pk2(fmaxf(a[ft].z, 0.f), fmaxf(a[ft].w, 0.f));
      *(u32x2*)(hb + hswz(j * 16 + ln15, fb * 2)) = pk;
    }
  }

  // ---- Layer 2, all 17 joints; packed h2 kept in registers (in-wave WAR:
  //      all h1 reads precede all h2 writes in program order; DS is in-order
  //      per wave and same-array aliasing pins the compiler's order) ----
  u32x2 pkh2[17][4];
#pragma unroll
  for (int j = 0; j < 17; j++) {
    f32x4 a[4];
#pragma unroll
    for (int ft = 0; ft < 4; ft++) a[ft] = (f32x4){0.f, 0.f, 0.f, 0.f};
#pragma unroll
    for (int s = 0; s < 4; s++)
      if (s < kDEG[j]) {
        const int i = kNBR[j][s];
#pragma unroll
        for (int kk = 0; kk < 2; kk++) {
          short8 bf = *(const short8*)(hb + hswz(i * 16 + ln15, kk * 64 + quad * 16));
#pragma unroll
          for (int ft = 0; ft < 4; ft++)
            a[ft] = mfma16(w2f[kk][ft], bf, a[ft]);
        }
      }
    const float w = kRDEG[kDEG[j]];
#pragma unroll
    for (int ft = 0; ft < 4; ft++) {
      u32x2 pk;
      pk.x = pk2(fmaxf(a[ft].x * w + bv2[ft].x, 0.f),
                 fmaxf(a[ft].y * w + bv2[ft].y, 0.f));
      pk.y = pk2(fmaxf(a[ft].z * w + bv2[ft].z, 0.f),
                 fmaxf(a[ft].w * w + bv2[ft].w, 0.f));
      pkh2[j][ft] = pk;
    }
  }

  // ---- Mb pool-stream prefetch, 24 fragments deep (overlaps h2 writeback) ----
  const short8* mrow = ((const short8*)Mb) + lane;
  short8 pf[24];
#pragma unroll
  for (int k5 = 0; k5 < 6; k5++)
#pragma unroll
    for (int w4 = 0; w4 < 4; w4++)
      pf[k5 * 4 + w4] = mrow[(w4 * 34 + k5) * 64];

  // ---- h2 writeback (pure ds_writes of prepacked values) ----
#pragma unroll
  for (int j = 0; j < 17; j++)
#pragma unroll
    for (int ft = 0; ft < 4; ft++) {
      int fb = ft * 16 + quad * 4;
      *(u32x2*)(hb + hswz(j * 16 + ln15, fb * 2)) = pkh2[j][ft];
    }

  // ---- Pool (folded layer3+pool1): all 4 f-blocks, 8 acc chains ----
  f32x4 pacc[4][2];
#pragma unroll
  for (int w4 = 0; w4 < 4; w4++) {
    pacc[w4][0] = *(const f32x4*)(bp1p + w4 * 16 + quad * 4);  // bias in chain 0
    pacc[w4][1] = (f32x4){0.f, 0.f, 0.f, 0.f};
  }
#pragma unroll
  for (int kk = 0; kk < 34; kk++) {
    const int i = kk >> 1;
    short8 bf = *(const short8*)(hb + hswz(i * 16 + ln15, (kk & 1) * 64 + quad * 16));
#pragma unroll
    for (int w4 = 0; w4 < 4; w4++) {
      short8 af = pf[(4 * kk + w4) % 24];
      if (kk + 6 < 34) pf[(4 * kk + w4) % 24] = mrow[(w4 * 34 + kk + 6) * 64];
      pacc[w4][kk & 1] = mfma16(af, bf, pacc[w4][kk & 1]);
    }
  }
  f32x4 zcv[4];
#pragma unroll
  for (int w4 = 0; w4 < 4; w4++) zcv[w4] = pacc[w4][0] + pacc[w4][1];

  // ---- Wp2 fragments + bp2 prefetch; then z pack into zb (xs overlay) ----
  short8 wp2f[16][2];
#pragma unroll
  for (int t = 0; t < 16; t++) {
    wp2f[t][0] = *(const short8*)(Wp2b + (t * 16 + ln15) * 64 + quad * 8);
    wp2f[t][1] = *(const short8*)(Wp2b + (t * 16 + ln15) * 64 + 32 + quad * 8);
  }
  char* zbB = (char*)xs;  // xs dead since L1
#pragma unroll
  for (int w4 = 0; w4 < 4; w4++) {
    int fb = w4 * 16 + quad * 4;
    u32x2 pk;
    pk.x = pk2(fmaxf(zcv[w4].x, 0.f), fmaxf(zcv[w4].y, 0.f));
    pk.y = pk2(fmaxf(zcv[w4].z, 0.f), fmaxf(zcv[w4].w, 0.f));
    *(u32x2*)(zbB + hswz(ln15, fb * 2)) = pk;
  }

  // ---- Pool layer 2: out = Wp2 * z + bp2 (zb read is intra-wave ordered) ----
  short8 bf0 = *(const short8*)(zbB + hswz(ln15, quad * 16));
  short8 bf1 = *(const short8*)(zbB + hswz(ln15, 64 + quad * 16));
#pragma unroll
  for (int t = 0; t < 16; t++) {
    f32x4 a = (f32x4){0.f, 0.f, 0.f, 0.f};
    a = mfma16(wp2f[t][0], bf0, a);
    a = mfma16(wp2f[t][1], bf1, a);
    int ob = t * 16 + quad * 4;
    f32x4 bv = *(const f32x4*)&bp2g[ob];
    f32x4 res = a + bv;
    *(f32x4*)(OUT + (size_t)(e0 + ln15) * 256 + ob) = res;
  }
}

extern "C" void kernel_launch(void* const* d_in, const int* in_sizes, int n_in,
                              void* d_out, int out_size, void* d_ws, size_t ws_size,
                              hipStream_t stream) {
  const float* X = (const float*)d_in[0];
  const float* W1 = (const float*)d_in[2];
  const float* b1 = (const float*)d_in[3];
  const float* W2 = (const float*)d_in[4];
  const float* b2 = (const float*)d_in[5];
  const float* W3 = (const float*)d_in[6];
  const float* b3 = (const float*)d_in[7];
  const float* Wp1 = (const float*)d_in[8];
  const float* bp1 = (const float*)d_in[9];
  const float* Wp2 = (const float*)d_in[10];
  const float* bp2 = (const float*)d_in[11];
  float* OUT = (float*)d_out;
  const int B = in_sizes[0] / 51;

  char* ws = (char*)d_ws;
  short* Mb = (short*)(ws + 0);          // 64*1088*2 = 139264 (swizzled)
  short* Wp2b = (short*)(ws + 139264);   // 32768
  short* W2b = (short*)(ws + 172032);    // 8192
  short* W1b = (short*)(ws + 180224);    // 1024 (k=3 slot = b1)
  float* bp1p = (float*)(ws + 181248);   // 256

  prep<<<370, 256, 0, stream>>>(W1, W2, Wp2, W3, Wp1, b3, bp1, b1,
                                W1b, W2b, Wp2b, Mb, bp1p);
  gcn_main<<<B / 16, 64, 0, stream>>>(X, Mb, Wp2b, W2b, W1b, bp1p,
                                      b2, bp2, OUT);
}

// Round 8
// 159.194 us; speedup vs baseline: 1.1830x; 1.1830x over previous
//
#include <hip/hip_runtime.h>
#include <hip/hip_bf16.h>
#include <stdint.h>

typedef __attribute__((ext_vector_type(8))) short short8;
typedef __attribute__((ext_vector_type(4))) float f32x4;
typedef __attribute__((ext_vector_type(4))) unsigned int u32x4;
typedef __attribute__((ext_vector_type(2))) unsigned int u32x2;

// Skeleton (fixed in reference) — constexpr so fully-unrolled loops fold
// every index/degree/offset into immediates.
constexpr int kNBR[17][4] = {
    {7, 1, 4, 0}, {0, 2, 0, 0}, {1, 3, 0, 0}, {2, 0, 0, 0},
    {0, 5, 0, 0}, {4, 6, 0, 0}, {5, 0, 0, 0}, {0, 8, 0, 0},
    {7, 9, 11, 14}, {8, 10, 0, 0}, {9, 0, 0, 0}, {8, 12, 0, 0},
    {11, 13, 0, 0}, {12, 0, 0, 0}, {8, 15, 0, 0}, {14, 16, 0, 0},
    {15, 0, 0, 0}};
constexpr int kDEG[17] = {3,2,2,1,2,2,1,2,4,2,1,2,2,1,2,2,1};
constexpr float kRDEG[5] = {0.f, 1.f, 0.5f, 0.33333334f, 0.25f};

__device__ inline unsigned short f2bf(float f) {
  union { float f; uint32_t u; } v; v.f = f;
  uint32_t u = v.u;
  uint32_t r = u + 0x7fffu + ((u >> 16) & 1u);  // RNE
  return (unsigned short)(r >> 16);
}
// hardware v_cvt_pk_bf16_f32 (RNE), a in low 16, b in high 16
__device__ inline uint32_t pk2(float a, float b) {
  union { __hip_bfloat162 h; uint32_t u; } v;
  v.h = __float22bfloat162_rn(make_float2(a, b));
  return v.u;
}
__device__ inline f32x4 mfma16(short8 a, short8 b, f32x4 c) {
  return __builtin_amdgcn_mfma_f32_16x16x32_bf16(a, b, c, 0, 0, 0);
}
__device__ inline int hswz(int row, int cb) {
  return row * 128 + (cb ^ ((row & 7) << 4));
}

// ---------------- prep kernel (unchanged from R5) ----------------
__global__ void prep(const float* __restrict__ W1,
                     const float* __restrict__ W2,
                     const float* __restrict__ Wp2,
                     const float* __restrict__ W3,
                     const float* __restrict__ Wp1,
                     const float* __restrict__ b3,
                     const float* __restrict__ bp1,
                     const float* __restrict__ b1,
                     short* __restrict__ W1b,
                     short* __restrict__ W2b,
                     short* __restrict__ Wp2b,
                     short* __restrict__ Mb,
                     float* __restrict__ bp1p) {
  __shared__ float w3s[4096];
  __shared__ float Qs[256];
  const int tid = threadIdx.x;
  const int bx = blockIdx.x;
  if (bx < 272) {
    for (int q = tid; q < 4096; q += 256) w3s[q] = W3[q];
    {
      int ro = tid >> 6, k = tid & 63;
      int r = bx * 4 + ro;
      int f = r / 17, i = r - f * 17;
      int dj = kDEG[i];
      float s = 0.f;
#pragma unroll
      for (int t = 0; t < 4; t++) {
        if (t < dj) {
          int nb = kNBR[i][t];
          s += kRDEG[kDEG[nb]] * Wp1[f * 1088 + nb * 64 + k];
        }
      }
      Qs[ro * 64 + k] = s;
    }
    __syncthreads();
    {
      int ro = tid >> 6, c = tid & 63;
      int r = bx * 4 + ro;
      int f = r / 17, i = r - f * 17;
      float s = 0.f;
#pragma unroll
      for (int k = 0; k < 64; k++) s += Qs[ro * 64 + k] * w3s[k * 64 + c];
      int col = i * 64 + c;
      int kk = col >> 5, qq = (col >> 3) & 3, cb = col & 7;
      int w = f >> 4, l15 = f & 15;
      Mb[(((w * 34 + kk) * 64) + qq * 16 + l15) * 8 + cb] = (short)f2bf(s);
    }
  } else if (bx < 354) {
    int q = (bx - 272) * 256 + tid;
    if (q < 4096) W2b[q] = (short)f2bf(W2[q]);
    int q2 = q - 4096;
    if (q2 >= 0 && q2 < 16384) Wp2b[q2] = (short)f2bf(Wp2[q2]);
    int q3 = q - 20480;
    if (q3 >= 0 && q3 < 512) {
      int k = q3 & 7, row = q3 >> 3;
      short v = 0;
      if (k < 3) v = (short)f2bf(W1[row * 3 + k]);
      else if (k == 3) v = (short)f2bf(b1[row]);  // bias in spare K-slot
      W1b[q3] = v;
    }
  } else {
    int wv = tid >> 6, l = tid & 63;
    int f = (bx - 354) * 4 + wv;
    float s = 0.f;
#pragma unroll
    for (int i = 0; i < 17; i++) s += Wp1[f * 1088 + i * 64 + l] * b3[l];
#pragma unroll
    for (int off = 32; off > 0; off >>= 1) s += __shfl_down(s, off);
    if (l == 0) bp1p[f] = bp1[f] + s;
  }
}

// ---------------- per-wave specialized body ----------------
// 2-wave block, single 16-elem tile. Joint split {0..7}/{8..16} cuts only
// the (7,8) edge -> near-balanced waves (deg 15/17, joints 8/9; R5's L1
// phase was 3-vs-5 joints = 67% imbalance). Barriers sync just 2 waves;
// 4 independent blocks/CU stagger to fill each other's drains. Both waves
// execute the identical barrier sequence.
template <int WIDX, int J0, int NJ>
__device__ __forceinline__ void waveBody(
    const short* __restrict__ Mb, const short* __restrict__ Wp2b,
    const short* __restrict__ W2b, const float* __restrict__ bp2g,
    float* __restrict__ OUT, short* hbuf, float* xs, float* sbias,
    const short8 (&w1f)[4], int bx, int lane, int ln15, int quad) {
  char* hb = (char*)hbuf;

  // ---- Layer 1 (fused agg0; b1 via K-slot; relu+pack epilogue) ----
#pragma unroll
  for (int jj = 0; jj < NJ; jj++) {
    const int j = J0 + jj;
    const int dj = kDEG[j];
    const float w = kRDEG[dj];
    union { short8 s; u32x4 u; } fr;
    fr.u = (u32x4){0u, 0u, 0u, 0u};
    if (quad == 0) {
      float s0, s1, s2;
      {
        int b = ln15 * 51 + kNBR[j][0] * 3;
        s0 = xs[b]; s1 = xs[b + 1]; s2 = xs[b + 2];
      }
      if (dj > 1) {
        int b = ln15 * 51 + kNBR[j][1] * 3;
        s0 += xs[b]; s1 += xs[b + 1]; s2 += xs[b + 2];
      }
      if (dj > 2) {
        int b = ln15 * 51 + kNBR[j][2] * 3;
        s0 += xs[b]; s1 += xs[b + 1]; s2 += xs[b + 2];
      }
      if (dj > 3) {
        int b = ln15 * 51 + kNBR[j][3] * 3;
        s0 += xs[b]; s1 += xs[b + 1]; s2 += xs[b + 2];
      }
      fr.u.x = pk2(s0 * w, s1 * w);
      fr.u.y = pk2(s2 * w, 1.0f);  // k=3 = 1.0 activates bias row of W1b
    }
    f32x4 a[4];
#pragma unroll
    for (int ft = 0; ft < 4; ft++)
      a[ft] = mfma16(w1f[ft], fr.s, (f32x4){0.f, 0.f, 0.f, 0.f});
#pragma unroll
    for (int ft = 0; ft < 4; ft++) {
      int fb = ft * 16 + quad * 4;
      u32x2 pk;
      pk.x = pk2(fmaxf(a[ft].x, 0.f), fmaxf(a[ft].y, 0.f));
      pk.y = pk2(fmaxf(a[ft].z, 0.f), fmaxf(a[ft].w, 0.f));
      *(u32x2*)(hb + hswz(j * 16 + ln15, fb * 2)) = pk;
    }
  }
  __syncthreads();  // h1 ready

  // ---- Layer 2: accumulate per joint, pack IMMEDIATELY (only packed
  // u32x2 state crosses the WAR barrier) ----
  short8 w2f[2][4];
#pragma unroll
  for (int kk = 0; kk < 2; kk++)
#pragma unroll
    for (int ft = 0; ft < 4; ft++)
      w2f[kk][ft] = *(const short8*)(W2b + (ft * 16 + ln15) * 64 + kk * 32 + quad * 8);

  u32x2 pkh2[NJ][4];
#pragma unroll
  for (int jj = 0; jj < NJ; jj++) {
    const int j = J0 + jj;
    const int dj = kDEG[j];
    const float w = kRDEG[dj];
    f32x4 a[4];
#pragma unroll
    for (int ft = 0; ft < 4; ft++) a[ft] = (f32x4){0.f, 0.f, 0.f, 0.f};
#pragma unroll
    for (int s = 0; s < 4; s++)
      if (s < dj) {
        const int i = kNBR[j][s];
#pragma unroll
        for (int kk = 0; kk < 2; kk++) {
          short8 bf = *(const short8*)(hb + hswz(i * 16 + ln15, kk * 64 + quad * 16));
#pragma unroll
          for (int ft = 0; ft < 4; ft++)
            a[ft] = mfma16(w2f[kk][ft], bf, a[ft]);
        }
      }
#pragma unroll
    for (int ft = 0; ft < 4; ft++) {
      int fb = ft * 16 + quad * 4;
      f32x4 bv = *(const f32x4*)&sbias[fb];
      u32x2 pk;
      pk.x = pk2(fmaxf(a[ft].x * w + bv.x, 0.f), fmaxf(a[ft].y * w + bv.y, 0.f));
      pk.y = pk2(fmaxf(a[ft].z * w + bv.z, 0.f), fmaxf(a[ft].w * w + bv.w, 0.f));
      pkh2[jj][ft] = pk;
    }
  }
  // pool prefetch (2 f-block streams) before the WAR barrier: L2 latency
  // hides behind the barrier + h2 writeback
  const short8* mrow0 = ((const short8*)Mb) + (size_t)(2 * WIDX) * 34 * 64 + lane;
  const short8* mrow1 = ((const short8*)Mb) + (size_t)(2 * WIDX + 1) * 34 * 64 + lane;
  short8 pf0[6], pf1[6];
#pragma unroll
  for (int p = 0; p < 6; p++) {
    pf0[p] = mrow0[p * 64];
    pf1[p] = mrow1[p * 64];
  }
  __syncthreads();  // all h1 reads done before overwrite

  // ---- h2 writeback (pure ds_writes of prepacked values) ----
#pragma unroll
  for (int jj = 0; jj < NJ; jj++) {
    const int j = J0 + jj;
#pragma unroll
    for (int ft = 0; ft < 4; ft++) {
      int fb = ft * 16 + quad * 4;
      *(u32x2*)(hb + hswz(j * 16 + ln15, fb * 2)) = pkh2[jj][ft];
    }
  }
  __syncthreads();  // h2 ready

  // ---- Pool (folded layer3+pool1): one bf read feeds BOTH f-block MFMAs ----
  f32x4 zcv[2];
  {
    f32x4 pacc[2][2];
    pacc[0][0] = *(const f32x4*)&sbias[64 + (2 * WIDX) * 16 + quad * 4];
    pacc[1][0] = *(const f32x4*)&sbias[64 + (2 * WIDX + 1) * 16 + quad * 4];
    pacc[0][1] = (f32x4){0.f, 0.f, 0.f, 0.f};
    pacc[1][1] = (f32x4){0.f, 0.f, 0.f, 0.f};
#pragma unroll
    for (int kk = 0; kk < 34; kk++) {
      const int i = kk >> 1;
      short8 bf = *(const short8*)(hb + hswz(i * 16 + ln15, (kk & 1) * 64 + quad * 16));
      short8 af0 = pf0[kk % 6];
      if (kk + 6 < 34) pf0[kk % 6] = mrow0[(kk + 6) * 64];
      pacc[0][kk & 1] = mfma16(af0, bf, pacc[0][kk & 1]);
      short8 af1 = pf1[kk % 6];
      if (kk + 6 < 34) pf1[kk % 6] = mrow1[(kk + 6) * 64];
      pacc[1][kk & 1] = mfma16(af1, bf, pacc[1][kk & 1]);
    }
    zcv[0] = pacc[0][0] + pacc[0][1];
    zcv[1] = pacc[1][0] + pacc[1][1];
  }
  // prefetch Wp2 fragments (8 output tiles/wave); hides behind zb pack+barrier
  short8 wp2f[8][2];
#pragma unroll
  for (int t = 0; t < 8; t++) {
    int ot = WIDX + 2 * t;
    wp2f[t][0] = *(const short8*)(Wp2b + (ot * 16 + ln15) * 64 + quad * 8);
    wp2f[t][1] = *(const short8*)(Wp2b + (ot * 16 + ln15) * 64 + 32 + quad * 8);
  }
  char* zbB = (char*)xs;  // overlay: xs dead since L1
#pragma unroll
  for (int b = 0; b < 2; b++) {
    int fb = (2 * WIDX + b) * 16 + quad * 4;
    u32x2 pk;
    pk.x = pk2(fmaxf(zcv[b].x, 0.f), fmaxf(zcv[b].y, 0.f));
    pk.y = pk2(fmaxf(zcv[b].z, 0.f), fmaxf(zcv[b].w, 0.f));
    *(u32x2*)(zbB + hswz(ln15, fb * 2)) = pk;
  }
  __syncthreads();  // zb ready

  // ---- Pool layer 2: out = Wp2 * z + bp2 ----
  short8 bf0 = *(const short8*)(zbB + hswz(ln15, quad * 16));
  short8 bf1 = *(const short8*)(zbB + hswz(ln15, 64 + quad * 16));
  const int e0 = bx * 16;
#pragma unroll
  for (int t = 0; t < 8; t++) {
    int ot = WIDX + 2 * t;
    f32x4 a = (f32x4){0.f, 0.f, 0.f, 0.f};
    a = mfma16(wp2f[t][0], bf0, a);
    a = mfma16(wp2f[t][1], bf1, a);
    int ob = ot * 16 + quad * 4;
    f32x4 bv = *(const f32x4*)&bp2g[ob];
    f32x4 res = a + bv;
    *(f32x4*)(OUT + (size_t)(e0 + ln15) * 256 + ob) = res;
  }
}

// ---------------- main fused kernel ----------------
// 128 threads / 2 waves, ONE 16-elem tile. LDS = 34816 (hbuf) + 3264 (xs,
// zb overlay) + 512 (sbias) = 38592 B -> 4 blocks/CU = 8 waves/CU =
// 2 waves/SIMD (R6 showed 1/SIMD starves; R5 showed 2/SIMD suffices).
__launch_bounds__(128, 2)
__global__ void gcn_main(const float* __restrict__ X,
                         const short* __restrict__ Mb,
                         const short* __restrict__ Wp2b,
                         const short* __restrict__ W2b,
                         const short* __restrict__ W1b,
                         const float* __restrict__ bp1p,
                         const float* __restrict__ b2g,
                         const float* __restrict__ bp2g,
                         float* __restrict__ OUT) {
  __shared__ __align__(16) short hbuf[272 * 64];  // 34816 B (h1 -> h2 in place)
  __shared__ __align__(16) float xs[816];         // 3264 B; zb overlays late
  __shared__ __align__(16) float sbias[128];      // b2 | bp1p

  const int tid = threadIdx.x;
  const int wave = tid >> 6;
  const int lane = tid & 63;
  const int ln15 = lane & 15;
  const int quad = lane >> 4;
  const int bx = blockIdx.x;

  // ---- init ----
  for (int q = tid; q < 204; q += 128)
    ((f32x4*)xs)[q] = ((const f32x4*)(X + (size_t)bx * 816))[q];
  short8 w1f[4];
#pragma unroll
  for (int ft = 0; ft < 4; ft++)
    w1f[ft] = *(const short8*)(W1b + (ft * 16 + ln15) * 8);
  if (tid < 128) sbias[tid] = (tid < 64) ? b2g[tid] : bp1p[tid - 64];
  __syncthreads();  // xs, sbias ready

  if (wave == 0)
    waveBody<0, 0, 8>(Mb, Wp2b, W2b, bp2g, OUT, hbuf, xs, sbias, w1f, bx, lane, ln15, quad);
  else
    waveBody<1, 8, 9>(Mb, Wp2b, W2b, bp2g, OUT, hbuf, xs, sbias, w1f, bx, lane, ln15, quad);
}

extern "C" void kernel_launch(void* const* d_in, const int* in_sizes, int n_in,
                              void* d_out, int out_size, void* d_ws, size_t ws_size,
                              hipStream_t stream) {
  const float* X = (const float*)d_in[0];
  const float* W1 = (const float*)d_in[2];
  const float* b1 = (const float*)d_in[3];
  const float* W2 = (const float*)d_in[4];
  const float* b2 = (const float*)d_in[5];
  const float* W3 = (const float*)d_in[6];
  const float* b3 = (const float*)d_in[7];
  const float* Wp1 = (const float*)d_in[8];
  const float* bp1 = (const float*)d_in[9];
  const float* Wp2 = (const float*)d_in[10];
  const float* bp2 = (const float*)d_in[11];
  float* OUT = (float*)d_out;
  const int B = in_sizes[0] / 51;

  char* ws = (char*)d_ws;
  short* Mb = (short*)(ws + 0);          // 64*1088*2 = 139264 (swizzled)
  short* Wp2b = (short*)(ws + 139264);   // 32768
  short* W2b = (short*)(ws + 172032);    // 8192
  short* W1b = (short*)(ws + 180224);    // 1024 (k=3 slot = b1)
  float* bp1p = (float*)(ws + 181248);   // 256

  prep<<<370, 256, 0, stream>>>(W1, W2, Wp2, W3, Wp1, b3, bp1, b1,
                                W1b, W2b, Wp2b, Mb, bp1p);
  gcn_main<<<B / 16, 128, 0, stream>>>(X, Mb, Wp2b, W2b, W1b, bp1p,
                                       b2, bp2, OUT);
}

// Round 9
// 148.591 us; speedup vs baseline: 1.2675x; 1.0714x over previous
//
#include <hip/hip_runtime.h>
#include <hip/hip_bf16.h>
#include <stdint.h>

typedef __attribute__((ext_vector_type(8))) short short8;
typedef __attribute__((ext_vector_type(4))) float f32x4;
typedef __attribute__((ext_vector_type(4))) unsigned int u32x4;
typedef __attribute__((ext_vector_type(2))) unsigned int u32x2;

// Skeleton (fixed in reference) — constexpr so fully-unrolled loops fold
// every index/degree/offset into immediates.
constexpr int kNBR[17][4] = {
    {7, 1, 4, 0}, {0, 2, 0, 0}, {1, 3, 0, 0}, {2, 0, 0, 0},
    {0, 5, 0, 0}, {4, 6, 0, 0}, {5, 0, 0, 0}, {0, 8, 0, 0},
    {7, 9, 11, 14}, {8, 10, 0, 0}, {9, 0, 0, 0}, {8, 12, 0, 0},
    {11, 13, 0, 0}, {12, 0, 0, 0}, {8, 15, 0, 0}, {14, 16, 0, 0},
    {15, 0, 0, 0}};
constexpr int kDEG[17] = {3,2,2,1,2,2,1,2,4,2,1,2,2,1,2,2,1};
constexpr float kRDEG[5] = {0.f, 1.f, 0.5f, 0.33333334f, 0.25f};
// per-wave output-joint tiles, balanced so sum(deg) = 8 per wave
constexpr int kWNT[4] = {3, 4, 5, 5};
constexpr int kWJT[4][5] = {{8, 1, 2, 0, 0},
                            {0, 4, 5, 3, 0},
                            {7, 9, 11, 6, 10},
                            {12, 14, 15, 13, 16}};

__device__ inline unsigned short f2bf(float f) {
  union { float f; uint32_t u; } v; v.f = f;
  uint32_t u = v.u;
  uint32_t r = u + 0x7fffu + ((u >> 16) & 1u);  // RNE
  return (unsigned short)(r >> 16);
}
// hardware v_cvt_pk_bf16_f32 (RNE), a in low 16, b in high 16
__device__ inline uint32_t pk2(float a, float b) {
  union { __hip_bfloat162 h; uint32_t u; } v;
  v.h = __float22bfloat162_rn(make_float2(a, b));
  return v.u;
}
__device__ inline f32x4 mfma16(short8 a, short8 b, f32x4 c) {
  return __builtin_amdgcn_mfma_f32_16x16x32_bf16(a, b, c, 0, 0, 0);
}
__device__ inline int hswz(int row, int cb) {
  return row * 128 + (cb ^ ((row & 7) << 4));
}

// ---------------- prep kernel ----------------
// Mb2 layout change (R9): k-dimension of the pool GEMM permuted so that the
// pool's B-fragment is a pure register concatenation of the L2 C-fragment.
// For (f, joint i, feature c): h = c>>5 (k-chunk half), c5 = c&31,
// q = (c5>>2)&3 (quad), m = ((c5>>4)<<2)|(c5&3) (k-slot within lane).
// A-frag store: Mb2[(((f>>4)*17 + i)*2 + h)*64 + q*16 + (f&15)][m].
__global__ void prep(const float* __restrict__ W1,
                     const float* __restrict__ W2,
                     const float* __restrict__ Wp2,
                     const float* __restrict__ W3,
                     const float* __restrict__ Wp1,
                     const float* __restrict__ b3,
                     const float* __restrict__ bp1,
                     const float* __restrict__ b1,
                     short* __restrict__ W1b,
                     short* __restrict__ W2b,
                     short* __restrict__ Wp2b,
                     short* __restrict__ Mb,
                     float* __restrict__ bp1p) {
  __shared__ float w3s[4096];
  __shared__ float Qs[256];
  const int tid = threadIdx.x;
  const int bx = blockIdx.x;
  if (bx < 272) {
    for (int q = tid; q < 4096; q += 256) w3s[q] = W3[q];
    {
      int ro = tid >> 6, k = tid & 63;
      int r = bx * 4 + ro;
      int f = r / 17, i = r - f * 17;
      int dj = kDEG[i];
      float s = 0.f;
#pragma unroll
      for (int t = 0; t < 4; t++) {
        if (t < dj) {
          int nb = kNBR[i][t];
          s += kRDEG[kDEG[nb]] * Wp1[f * 1088 + nb * 64 + k];
        }
      }
      Qs[ro * 64 + k] = s;
    }
    __syncthreads();
    {
      int ro = tid >> 6, c = tid & 63;
      int r = bx * 4 + ro;
      int f = r / 17, i = r - f * 17;
      float s = 0.f;
#pragma unroll
      for (int k = 0; k < 64; k++) s += Qs[ro * 64 + k] * w3s[k * 64 + c];
      int h = c >> 5;
      int c5 = c & 31;
      int q = (c5 >> 2) & 3;
      int m = ((c5 >> 4) << 2) | (c5 & 3);
      int w = f >> 4, l15 = f & 15;
      Mb[((((w * 17 + i) * 2 + h) * 64) + q * 16 + l15) * 8 + m] = (short)f2bf(s);
    }
  } else if (bx < 354) {
    int q = (bx - 272) * 256 + tid;
    if (q < 4096) W2b[q] = (short)f2bf(W2[q]);
    int q2 = q - 4096;
    if (q2 >= 0 && q2 < 16384) Wp2b[q2] = (short)f2bf(Wp2[q2]);
    int q3 = q - 20480;
    if (q3 >= 0 && q3 < 512) {
      int k = q3 & 7, row = q3 >> 3;
      short v = 0;
      if (k < 3) v = (short)f2bf(W1[row * 3 + k]);
      else if (k == 3) v = (short)f2bf(b1[row]);  // bias in spare K-slot
      W1b[q3] = v;
    }
  } else {
    int wv = tid >> 6, l = tid & 63;
    int f = (bx - 354) * 4 + wv;
    float s = 0.f;
#pragma unroll
    for (int i = 0; i < 17; i++) s += Wp1[f * 1088 + i * 64 + l] * b3[l];
#pragma unroll
    for (int off = 32; off > 0; off >>= 1) s += __shfl_down(s, off);
    if (l == 0) bp1p[f] = bp1[f] + s;
  }
}

// ---------------- per-wave specialized body (R9) ----------------
// R5 structure (4 waves, dual 16-elem tiles) with the pool restructured:
// each wave pools ITS OWN joints' k-chunks (B-frag = register concat of its
// pkh2 — zero LDS) across all 4 output-f blocks, producing f32 partials;
// partials cross waves through a 32KB LDS region (overlaid on dead h1),
// reduced by all threads. Removes the h2 writeback phase + the pool's 68
// b128 LDS reads per wave. Barriers stay at 5, all waves uniform.
template <int WV>
__device__ __forceinline__ void waveBody(
    const short* __restrict__ Mb2, const short* __restrict__ Wp2b,
    const short* __restrict__ W2b, const float* __restrict__ bp2g,
    float* __restrict__ OUT, short* hbuf, float* xs, float* sbias,
    const short8 (&w1f)[4], int bx, int lane, int ln15, int quad) {
  constexpr int NT = kWNT[WV];
  char* hb0 = (char*)hbuf;

  // ---- Layer 1 (fused agg0; b1 via K-slot; relu+pack), dual tile ----
#pragma unroll
  for (int t = 0; t < NT; t++) {
    const int j = kWJT[WV][t];
    const int dj = kDEG[j];
    const float w = kRDEG[dj];
    union { short8 s; u32x4 u; } fr[2];
#pragma unroll
    for (int g = 0; g < 2; g++) {
      const float* xsg = xs + g * 816;
      fr[g].u = (u32x4){0u, 0u, 0u, 0u};
      if (quad == 0) {
        float s0, s1, s2;
        {
          int b = ln15 * 51 + kNBR[j][0] * 3;
          s0 = xsg[b]; s1 = xsg[b + 1]; s2 = xsg[b + 2];
        }
        if (dj > 1) {
          int b = ln15 * 51 + kNBR[j][1] * 3;
          s0 += xsg[b]; s1 += xsg[b + 1]; s2 += xsg[b + 2];
        }
        if (dj > 2) {
          int b = ln15 * 51 + kNBR[j][2] * 3;
          s0 += xsg[b]; s1 += xsg[b + 1]; s2 += xsg[b + 2];
        }
        if (dj > 3) {
          int b = ln15 * 51 + kNBR[j][3] * 3;
          s0 += xsg[b]; s1 += xsg[b + 1]; s2 += xsg[b + 2];
        }
        fr[g].u.x = pk2(s0 * w, s1 * w);
        fr[g].u.y = pk2(s2 * w, 1.0f);  // k=3 = 1.0 activates bias row of W1b
      }
    }
#pragma unroll
    for (int g = 0; g < 2; g++) {
      f32x4 a[4];
#pragma unroll
      for (int ft = 0; ft < 4; ft++)
        a[ft] = mfma16(w1f[ft], fr[g].s, (f32x4){0.f, 0.f, 0.f, 0.f});
#pragma unroll
      for (int ft = 0; ft < 4; ft++) {
        int fb = ft * 16 + quad * 4;
        u32x2 pk;
        pk.x = pk2(fmaxf(a[ft].x, 0.f), fmaxf(a[ft].y, 0.f));
        pk.y = pk2(fmaxf(a[ft].z, 0.f), fmaxf(a[ft].w, 0.f));
        *(u32x2*)(hb0 + g * 34816 + hswz(j * 16 + ln15, fb * 2)) = pk;
      }
    }
  }
  __syncthreads();  // h1 ready

  // ---- Layer 2 -> pkh2 (registers; final bf16 h2, never hits LDS) ----
  short8 w2f[2][4];
#pragma unroll
  for (int kk = 0; kk < 2; kk++)
#pragma unroll
    for (int ft = 0; ft < 4; ft++)
      w2f[kk][ft] = *(const short8*)(W2b + (ft * 16 + ln15) * 64 + kk * 32 + quad * 8);

  u32x2 pkh2[2][NT][4];
#pragma unroll
  for (int t = 0; t < NT; t++) {
    const int j = kWJT[WV][t];
    const int dj = kDEG[j];
    const float w = kRDEG[dj];
#pragma unroll
    for (int g = 0; g < 2; g++) {
      f32x4 a[4];
#pragma unroll
      for (int ft = 0; ft < 4; ft++) a[ft] = (f32x4){0.f, 0.f, 0.f, 0.f};
#pragma unroll
      for (int s = 0; s < 4; s++)
        if (s < dj) {
          const int i = kNBR[j][s];
#pragma unroll
          for (int kk = 0; kk < 2; kk++) {
            short8 bf = *(const short8*)(hb0 + g * 34816 +
                                         hswz(i * 16 + ln15, kk * 64 + quad * 16));
#pragma unroll
            for (int ft = 0; ft < 4; ft++)
              a[ft] = mfma16(w2f[kk][ft], bf, a[ft]);
          }
        }
#pragma unroll
      for (int ft = 0; ft < 4; ft++) {
        int fb = ft * 16 + quad * 4;
        f32x4 bv = *(const f32x4*)&sbias[fb];
        u32x2 pk;
        pk.x = pk2(fmaxf(a[ft].x * w + bv.x, 0.f), fmaxf(a[ft].y * w + bv.y, 0.f));
        pk.y = pk2(fmaxf(a[ft].z * w + bv.z, 0.f), fmaxf(a[ft].w * w + bv.w, 0.f));
        pkh2[g][t][ft] = pk;
      }
    }
  }

  // ---- Pool-partial: B-frag = pkh2 register concat (zero LDS traffic);
  //      A-frag streamed from the k-permuted Mb2. Covers all 4 f-blocks
  //      for this wave's own joints only. ----
  f32x4 zacc[4][2];
#pragma unroll
  for (int w4 = 0; w4 < 4; w4++) {
    zacc[w4][0] = (f32x4){0.f, 0.f, 0.f, 0.f};
    zacc[w4][1] = (f32x4){0.f, 0.f, 0.f, 0.f};
  }
  const short8* mb = (const short8*)Mb2;
#pragma unroll
  for (int t = 0; t < NT; t++) {
    const int i = kWJT[WV][t];
#pragma unroll
    for (int h = 0; h < 2; h++) {
      union { short8 s; u32x4 u; } bf0, bf1;
      bf0.u = (u32x4){pkh2[0][t][2 * h].x, pkh2[0][t][2 * h].y,
                      pkh2[0][t][2 * h + 1].x, pkh2[0][t][2 * h + 1].y};
      bf1.u = (u32x4){pkh2[1][t][2 * h].x, pkh2[1][t][2 * h].y,
                      pkh2[1][t][2 * h + 1].x, pkh2[1][t][2 * h + 1].y};
#pragma unroll
      for (int w4 = 0; w4 < 4; w4++) {
        short8 af = mb[(((w4 * 17 + i) * 2 + h) * 64) + lane];
        zacc[w4][0] = mfma16(af, bf0.s, zacc[w4][0]);
        zacc[w4][1] = mfma16(af, bf1.s, zacc[w4][1]);
      }
    }
  }
  __syncthreads();  // WAR: all h1 reads complete -> hbuf reusable for partials

  // ---- partial writeback (contiguous 1KB per instruction, conflict-free) ----
#pragma unroll
  for (int w4 = 0; w4 < 4; w4++)
#pragma unroll
    for (int g = 0; g < 2; g++)
      *(f32x4*)(hb0 + WV * 8192 + (w4 * 2 + g) * 1024 + lane * 16) = zacc[w4][g];

  // prefetch Wp2 fragments; latency hides behind the barrier
  short8 wp2f[4][2];
#pragma unroll
  for (int t = 0; t < 4; t++) {
    int ot = WV + 4 * t;
    wp2f[t][0] = *(const short8*)(Wp2b + (ot * 16 + ln15) * 64 + quad * 8);
    wp2f[t][1] = *(const short8*)(Wp2b + (ot * 16 + ln15) * 64 + 32 + quad * 8);
  }
  __syncthreads();  // partials ready

  // ---- cross-wave reduce: z = sum partials + bp1p, relu, pack -> zb ----
  char* zbB = (char*)xs;  // overlay: xs dead since L1
#pragma unroll
  for (int half = 0; half < 2; half++) {
    const int gw = WV + half * 4;  // (w4,g) slot: gw = w4*2+g
    const int g = gw & 1, w4 = gw >> 1;
    f32x4 s0 = *(const f32x4*)(hb0 + 0 * 8192 + gw * 1024 + lane * 16);
    f32x4 s1 = *(const f32x4*)(hb0 + 1 * 8192 + gw * 1024 + lane * 16);
    f32x4 s2 = *(const f32x4*)(hb0 + 2 * 8192 + gw * 1024 + lane * 16);
    f32x4 s3 = *(const f32x4*)(hb0 + 3 * 8192 + gw * 1024 + lane * 16);
    f32x4 s = (s0 + s1) + (s2 + s3);
    const int e = lane & 15, qd = lane >> 4;
    const int f0 = w4 * 16 + qd * 4;
    f32x4 bv = *(const f32x4*)&sbias[64 + f0];
    u32x2 pk;
    pk.x = pk2(fmaxf(s.x + bv.x, 0.f), fmaxf(s.y + bv.y, 0.f));
    pk.y = pk2(fmaxf(s.z + bv.z, 0.f), fmaxf(s.w + bv.w, 0.f));
    *(u32x2*)(zbB + g * 2048 + e * 128 + ((f0 * 2) ^ ((e & 7) << 4))) = pk;
  }
  __syncthreads();  // zb ready

  // ---- Pool layer 2: out = Wp2 * z + bp2, both tiles ----
  const int e0 = bx * 32;
#pragma unroll
  for (int g = 0; g < 2; g++) {
    short8 bf0 = *(const short8*)(zbB + g * 2048 + ln15 * 128 +
                                  ((quad * 16) ^ ((ln15 & 7) << 4)));
    short8 bf1 = *(const short8*)(zbB + g * 2048 + ln15 * 128 +
                                  ((64 + quad * 16) ^ ((ln15 & 7) << 4)));
    int e0g = e0 + g * 16;
#pragma unroll
    for (int t = 0; t < 4; t++) {
      int ot = WV + 4 * t;
      f32x4 a = mfma16(wp2f[t][0], bf0, (f32x4){0.f, 0.f, 0.f, 0.f});
      a = mfma16(wp2f[t][1], bf1, a);
      int ob = ot * 16 + quad * 4;
      f32x4 bv = *(const f32x4*)&bp2g[ob];
      f32x4 res = a + bv;
      *(f32x4*)(OUT + (size_t)(e0g + ln15) * 256 + ob) = res;
    }
  }
}

// ---------------- main fused kernel ----------------
// R5 shape: 256 threads / 4 waves, dual 16-elem tiles. LDS = 69632 (h1 dual
// tile; partials overlay its first 32KB after WAR) + 6528 (xs; zb overlay)
// + 512 (sbias) = 76672 -> 2 blocks/CU, 2 waves/SIMD.
__launch_bounds__(256, 2)
__global__ void gcn_main(const float* __restrict__ X,
                         const short* __restrict__ Mb2,
                         const short* __restrict__ Wp2b,
                         const short* __restrict__ W2b,
                         const short* __restrict__ W1b,
                         const float* __restrict__ bp1p,
                         const float* __restrict__ b2g,
                         const float* __restrict__ bp2g,
                         float* __restrict__ OUT) {
  __shared__ __align__(16) short hbuf[2 * 272 * 64];  // 69632 B
  __shared__ __align__(16) float xs[2 * 816];         // 6528 B; zb overlays late
  __shared__ __align__(16) float sbias[128];          // b2 | bp1p

  const int tid = threadIdx.x;
  const int wave = tid >> 6;
  const int lane = tid & 63;
  const int ln15 = lane & 15;
  const int quad = lane >> 4;
  const int bx = blockIdx.x;

  // ---- init ----
  for (int q = tid; q < 408; q += 256)
    ((f32x4*)xs)[q] = ((const f32x4*)(X + (size_t)bx * 1632))[q];
  short8 w1f[4];
#pragma unroll
  for (int ft = 0; ft < 4; ft++)
    w1f[ft] = *(const short8*)(W1b + (ft * 16 + ln15) * 8);
  if (tid < 128) sbias[tid] = (tid < 64) ? b2g[tid] : bp1p[tid - 64];
  __syncthreads();  // xs, sbias ready

  if (wave == 0)
    waveBody<0>(Mb2, Wp2b, W2b, bp2g, OUT, hbuf, xs, sbias, w1f, bx, lane, ln15, quad);
  else if (wave == 1)
    waveBody<1>(Mb2, Wp2b, W2b, bp2g, OUT, hbuf, xs, sbias, w1f, bx, lane, ln15, quad);
  else if (wave == 2)
    waveBody<2>(Mb2, Wp2b, W2b, bp2g, OUT, hbuf, xs, sbias, w1f, bx, lane, ln15, quad);
  else
    waveBody<3>(Mb2, Wp2b, W2b, bp2g, OUT, hbuf, xs, sbias, w1f, bx, lane, ln15, quad);
}

extern "C" void kernel_launch(void* const* d_in, const int* in_sizes, int n_in,
                              void* d_out, int out_size, void* d_ws, size_t ws_size,
                              hipStream_t stream) {
  const float* X = (const float*)d_in[0];
  const float* W1 = (const float*)d_in[2];
  const float* b1 = (const float*)d_in[3];
  const float* W2 = (const float*)d_in[4];
  const float* b2 = (const float*)d_in[5];
  const float* W3 = (const float*)d_in[6];
  const float* b3 = (const float*)d_in[7];
  const float* Wp1 = (const float*)d_in[8];
  const float* bp1 = (const float*)d_in[9];
  const float* Wp2 = (const float*)d_in[10];
  const float* bp2 = (const float*)d_in[11];
  float* OUT = (float*)d_out;
  const int B = in_sizes[0] / 51;

  char* ws = (char*)d_ws;
  short* Mb = (short*)(ws + 0);          // 64*1088*2 = 139264 (k-permuted)
  short* Wp2b = (short*)(ws + 139264);   // 32768
  short* W2b = (short*)(ws + 172032);    // 8192
  short* W1b = (short*)(ws + 180224);    // 1024 (k=3 slot = b1)
  float* bp1p = (float*)(ws + 181248);   // 256

  prep<<<370, 256, 0, stream>>>(W1, W2, Wp2, W3, Wp1, b3, bp1, b1,
                                W1b, W2b, Wp2b, Mb, bp1p);
  gcn_main<<<B / 32, 256, 0, stream>>>(X, Mb, Wp2b, W2b, W1b, bp1p,
                                       b2, bp2, OUT);
}

// Round 10
// 147.609 us; speedup vs baseline: 1.2759x; 1.0066x over previous
//
#include <hip/hip_runtime.h>
#include <hip/hip_bf16.h>
#include <stdint.h>

typedef __attribute__((ext_vector_type(8))) short short8;
typedef __attribute__((ext_vector_type(4))) float f32x4;
typedef __attribute__((ext_vector_type(4))) unsigned int u32x4;
typedef __attribute__((ext_vector_type(2))) unsigned int u32x2;

// Skeleton (fixed in reference) — constexpr so fully-unrolled loops fold
// every index/degree/offset into immediates.
constexpr int kNBR[17][4] = {
    {7, 1, 4, 0}, {0, 2, 0, 0}, {1, 3, 0, 0}, {2, 0, 0, 0},
    {0, 5, 0, 0}, {4, 6, 0, 0}, {5, 0, 0, 0}, {0, 8, 0, 0},
    {7, 9, 11, 14}, {8, 10, 0, 0}, {9, 0, 0, 0}, {8, 12, 0, 0},
    {11, 13, 0, 0}, {12, 0, 0, 0}, {8, 15, 0, 0}, {14, 16, 0, 0},
    {15, 0, 0, 0}};
constexpr int kDEG[17] = {3,2,2,1,2,2,1,2,4,2,1,2,2,1,2,2,1};
constexpr float kRDEG[5] = {0.f, 1.f, 0.5f, 0.33333334f, 0.25f};
// per-wave output-joint tiles, balanced so sum(deg) = 8 per wave (this is
// now also the L1 neighbor-instance count per wave -> L1 perfectly balanced)
constexpr int kWNT[4] = {3, 4, 5, 5};
constexpr int kWJT[4][5] = {{8, 1, 2, 0, 0},
                            {0, 4, 5, 3, 0},
                            {7, 9, 11, 6, 10},
                            {12, 14, 15, 13, 16}};

__device__ inline unsigned short f2bf(float f) {
  union { float f; uint32_t u; } v; v.f = f;
  uint32_t u = v.u;
  uint32_t r = u + 0x7fffu + ((u >> 16) & 1u);  // RNE
  return (unsigned short)(r >> 16);
}
// hardware v_cvt_pk_bf16_f32 (RNE), a in low 16, b in high 16
__device__ inline uint32_t pk2(float a, float b) {
  union { __hip_bfloat162 h; uint32_t u; } v;
  v.h = __float22bfloat162_rn(make_float2(a, b));
  return v.u;
}
__device__ inline f32x4 mfma16(short8 a, short8 b, f32x4 c) {
  return __builtin_amdgcn_mfma_f32_16x16x32_bf16(a, b, c, 0, 0, 0);
}

// ---------------- prep kernel ----------------
// R10: W2 and Wp2 k-dimensions get the SAME permutation as Mb2 (R9-proven):
// for input feature c: h = c>>5, c5 = c&31, q = (c5>>2)&3,
// m = ((c5>>4)<<2)|(c5&3); element stored at [row*64 + h*32 + q*8 + m].
// This makes the packed C-fragment of the producing MFMA (u32x2 pairs)
// directly usable as the consuming MFMA's B-fragment via register concat.
__global__ void prep(const float* __restrict__ W1,
                     const float* __restrict__ W2,
                     const float* __restrict__ Wp2,
                     const float* __restrict__ W3,
                     const float* __restrict__ Wp1,
                     const float* __restrict__ b3,
                     const float* __restrict__ bp1,
                     const float* __restrict__ b1,
                     short* __restrict__ W1b,
                     short* __restrict__ W2b,
                     short* __restrict__ Wp2b,
                     short* __restrict__ Mb,
                     float* __restrict__ bp1p) {
  __shared__ float w3s[4096];
  __shared__ float Qs[256];
  const int tid = threadIdx.x;
  const int bx = blockIdx.x;
  if (bx < 272) {
    for (int q = tid; q < 4096; q += 256) w3s[q] = W3[q];
    {
      int ro = tid >> 6, k = tid & 63;
      int r = bx * 4 + ro;
      int f = r / 17, i = r - f * 17;
      int dj = kDEG[i];
      float s = 0.f;
#pragma unroll
      for (int t = 0; t < 4; t++) {
        if (t < dj) {
          int nb = kNBR[i][t];
          s += kRDEG[kDEG[nb]] * Wp1[f * 1088 + nb * 64 + k];
        }
      }
      Qs[ro * 64 + k] = s;
    }
    __syncthreads();
    {
      int ro = tid >> 6, c = tid & 63;
      int r = bx * 4 + ro;
      int f = r / 17, i = r - f * 17;
      float s = 0.f;
#pragma unroll
      for (int k = 0; k < 64; k++) s += Qs[ro * 64 + k] * w3s[k * 64 + c];
      int h = c >> 5;
      int c5 = c & 31;
      int q = (c5 >> 2) & 3;
      int m = ((c5 >> 4) << 2) | (c5 & 3);
      int w = f >> 4, l15 = f & 15;
      Mb[((((w * 17 + i) * 2 + h) * 64) + q * 16 + l15) * 8 + m] = (short)f2bf(s);
    }
  } else if (bx < 354) {
    int q = (bx - 272) * 256 + tid;
    if (q < 4096) {  // W2 k-permuted
      int r = q >> 6, c = q & 63;
      int h = c >> 5, c5 = c & 31;
      int qq = (c5 >> 2) & 3, m = ((c5 >> 4) << 2) | (c5 & 3);
      W2b[r * 64 + h * 32 + qq * 8 + m] = (short)f2bf(W2[q]);
    }
    int q2 = q - 4096;
    if (q2 >= 0 && q2 < 16384) {  // Wp2 k-permuted
      int r = q2 >> 6, c = q2 & 63;
      int h = c >> 5, c5 = c & 31;
      int qq = (c5 >> 2) & 3, m = ((c5 >> 4) << 2) | (c5 & 3);
      Wp2b[r * 64 + h * 32 + qq * 8 + m] = (short)f2bf(Wp2[q2]);
    }
    int q3 = q - 20480;
    if (q3 >= 0 && q3 < 512) {
      int k = q3 & 7, row = q3 >> 3;
      short v = 0;
      if (k < 3) v = (short)f2bf(W1[row * 3 + k]);
      else if (k == 3) v = (short)f2bf(b1[row]);  // bias in spare K-slot
      W1b[q3] = v;
    }
  } else {
    int wv = tid >> 6, l = tid & 63;
    int f = (bx - 354) * 4 + wv;
    float s = 0.f;
#pragma unroll
    for (int i = 0; i < 17; i++) s += Wp1[f * 1088 + i * 64 + l] * b3[l];
#pragma unroll
    for (int off = 32; off > 0; off >>= 1) s += __shfl_down(s, off);
    if (l == 0) bp1p[f] = bp1[f] + s;
  }
}

// ---------------- per-wave specialized body (R10) ----------------
// Fully register-resident activation chain: each wave computes h1 for its
// own joints' NEIGHBORS itself (8 neighbor-instances/wave, exactly balanced),
// keeps packed ph1 in registers, feeds L2 via register-concat B-frags
// (k-permuted W2), producing pkh2 in registers -> pool via Mb2 (R9 path) ->
// f32 partials through LDS (the only cross-wave data) -> every wave
// redundantly reduces all 8 slots -> z in registers -> pool2 via register
// concat (k-permuted Wp2). h1/h2/z NEVER touch LDS. TWO barriers total.
template <int WV>
__device__ __forceinline__ void waveBody(
    const short* __restrict__ Mb2, const short* __restrict__ Wp2p,
    const short* __restrict__ W2p, const float* __restrict__ bp2g,
    float* __restrict__ OUT, float* __restrict__ pbuf,
    float* __restrict__ xs, float* __restrict__ sbias,
    const short8 (&w1f)[4], int bx, int lane, int ln15, int quad) {
  constexpr int NT = kWNT[WV];

  short8 w2f[2][4];
#pragma unroll
  for (int h = 0; h < 2; h++)
#pragma unroll
    for (int ft = 0; ft < 4; ft++)
      w2f[h][ft] = *(const short8*)(W2p + (ft * 16 + ln15) * 64 + h * 32 + quad * 8);

  // ---- L1 (per-neighbor, register-resident) + L2 (register concat) ----
  u32x2 pkh2[2][NT][4];
#pragma unroll
  for (int t = 0; t < NT; t++) {
    const int j = kWJT[WV][t];
    const int dj = kDEG[j];
    const float wj = kRDEG[dj];
    u32x2 ph1[4][2][4];  // [neighbor][g][ft], only [0..dj) used (static idx)
#pragma unroll
    for (int s = 0; s < 4; s++) {
      if (s < dj) {
        const int i = kNBR[j][s];
        const int di = kDEG[i];
        const float wi = kRDEG[di];
#pragma unroll
        for (int g = 0; g < 2; g++) {
          const float* xsg = xs + g * 816;
          union { short8 s8; u32x4 u; } fr;
          fr.u = (u32x4){0u, 0u, 0u, 0u};
          if (quad == 0) {
            float s0, s1, s2;
            {
              int b = ln15 * 51 + kNBR[i][0] * 3;
              s0 = xsg[b]; s1 = xsg[b + 1]; s2 = xsg[b + 2];
            }
            if (di > 1) {
              int b = ln15 * 51 + kNBR[i][1] * 3;
              s0 += xsg[b]; s1 += xsg[b + 1]; s2 += xsg[b + 2];
            }
            if (di > 2) {
              int b = ln15 * 51 + kNBR[i][2] * 3;
              s0 += xsg[b]; s1 += xsg[b + 1]; s2 += xsg[b + 2];
            }
            if (di > 3) {
              int b = ln15 * 51 + kNBR[i][3] * 3;
              s0 += xsg[b]; s1 += xsg[b + 1]; s2 += xsg[b + 2];
            }
            fr.u.x = pk2(s0 * wi, s1 * wi);
            fr.u.y = pk2(s2 * wi, 1.0f);  // k=3 = 1.0 activates bias row
          }
          f32x4 a[4];
#pragma unroll
          for (int ft = 0; ft < 4; ft++)
            a[ft] = mfma16(w1f[ft], fr.s8, (f32x4){0.f, 0.f, 0.f, 0.f});
#pragma unroll
          for (int ft = 0; ft < 4; ft++) {
            u32x2 pk;
            pk.x = pk2(fmaxf(a[ft].x, 0.f), fmaxf(a[ft].y, 0.f));
            pk.y = pk2(fmaxf(a[ft].z, 0.f), fmaxf(a[ft].w, 0.f));
            ph1[s][g][ft] = pk;
          }
        }
      }
    }
#pragma unroll
    for (int g = 0; g < 2; g++) {
      f32x4 a[4];
#pragma unroll
      for (int ft = 0; ft < 4; ft++) a[ft] = (f32x4){0.f, 0.f, 0.f, 0.f};
#pragma unroll
      for (int s = 0; s < 4; s++)
        if (s < dj) {
#pragma unroll
          for (int h = 0; h < 2; h++) {
            union { short8 s8; u32x4 u; } bf;
            bf.u = (u32x4){ph1[s][g][2 * h].x, ph1[s][g][2 * h].y,
                           ph1[s][g][2 * h + 1].x, ph1[s][g][2 * h + 1].y};
#pragma unroll
            for (int ft = 0; ft < 4; ft++)
              a[ft] = mfma16(w2f[h][ft], bf.s8, a[ft]);
          }
        }
#pragma unroll
      for (int ft = 0; ft < 4; ft++) {
        int fb = ft * 16 + quad * 4;
        f32x4 bv = *(const f32x4*)&sbias[fb];
        u32x2 pk;
        pk.x = pk2(fmaxf(a[ft].x * wj + bv.x, 0.f), fmaxf(a[ft].y * wj + bv.y, 0.f));
        pk.y = pk2(fmaxf(a[ft].z * wj + bv.z, 0.f), fmaxf(a[ft].w * wj + bv.w, 0.f));
        pkh2[g][t][ft] = pk;
      }
    }
  }

  // ---- Pool-partial (R9 path): B = pkh2 concat, A streamed from Mb2 ----
  f32x4 zacc[4][2];
#pragma unroll
  for (int w4 = 0; w4 < 4; w4++) {
    zacc[w4][0] = (f32x4){0.f, 0.f, 0.f, 0.f};
    zacc[w4][1] = (f32x4){0.f, 0.f, 0.f, 0.f};
  }
  const short8* mb = (const short8*)Mb2;
#pragma unroll
  for (int t = 0; t < NT; t++) {
    const int i = kWJT[WV][t];
#pragma unroll
    for (int h = 0; h < 2; h++) {
      union { short8 s8; u32x4 u; } bf0, bf1;
      bf0.u = (u32x4){pkh2[0][t][2 * h].x, pkh2[0][t][2 * h].y,
                      pkh2[0][t][2 * h + 1].x, pkh2[0][t][2 * h + 1].y};
      bf1.u = (u32x4){pkh2[1][t][2 * h].x, pkh2[1][t][2 * h].y,
                      pkh2[1][t][2 * h + 1].x, pkh2[1][t][2 * h + 1].y};
#pragma unroll
      for (int w4 = 0; w4 < 4; w4++) {
        short8 af = mb[(((w4 * 17 + i) * 2 + h) * 64) + lane];
        zacc[w4][0] = mfma16(af, bf0.s8, zacc[w4][0]);
        zacc[w4][1] = mfma16(af, bf1.s8, zacc[w4][1]);
      }
    }
  }
  // ---- partial writeback (contiguous 1KB per slot, conflict-free) ----
#pragma unroll
  for (int w4 = 0; w4 < 4; w4++)
#pragma unroll
    for (int g = 0; g < 2; g++)
      *(f32x4*)(pbuf + WV * 2048 + (w4 * 2 + g) * 256 + lane * 4) = zacc[w4][g];
  // prefetch Wp2 fragments; latency hides behind the barrier
  short8 wp2f[4][2];
#pragma unroll
  for (int t = 0; t < 4; t++) {
    int ot = WV + 4 * t;
    wp2f[t][0] = *(const short8*)(Wp2p + (ot * 16 + ln15) * 64 + quad * 8);
    wp2f[t][1] = *(const short8*)(Wp2p + (ot * 16 + ln15) * 64 + 32 + quad * 8);
  }
  __syncthreads();  // partials ready (barrier #2 of 2)

  // ---- redundant full reduce: z in registers (no zb exchange) ----
  u32x2 zp[2][4];
#pragma unroll
  for (int w4 = 0; w4 < 4; w4++) {
    f32x4 bv = *(const f32x4*)&sbias[64 + w4 * 16 + quad * 4];
#pragma unroll
    for (int g = 0; g < 2; g++) {
      const int gw = w4 * 2 + g;
      f32x4 s0 = *(const f32x4*)(pbuf + 0 * 2048 + gw * 256 + lane * 4);
      f32x4 s1 = *(const f32x4*)(pbuf + 1 * 2048 + gw * 256 + lane * 4);
      f32x4 s2 = *(const f32x4*)(pbuf + 2 * 2048 + gw * 256 + lane * 4);
      f32x4 s3 = *(const f32x4*)(pbuf + 3 * 2048 + gw * 256 + lane * 4);
      f32x4 s = (s0 + s1) + (s2 + s3);
      u32x2 pk;
      pk.x = pk2(fmaxf(s.x + bv.x, 0.f), fmaxf(s.y + bv.y, 0.f));
      pk.y = pk2(fmaxf(s.z + bv.z, 0.f), fmaxf(s.w + bv.w, 0.f));
      zp[g][w4] = pk;
    }
  }

  // ---- Pool layer 2: B = zp concat (k-permuted Wp2), both tiles ----
  const int e0 = bx * 32;
#pragma unroll
  for (int g = 0; g < 2; g++) {
    union { short8 s8; u32x4 u; } bf0, bf1;
    bf0.u = (u32x4){zp[g][0].x, zp[g][0].y, zp[g][1].x, zp[g][1].y};
    bf1.u = (u32x4){zp[g][2].x, zp[g][2].y, zp[g][3].x, zp[g][3].y};
    int e0g = e0 + g * 16;
#pragma unroll
    for (int t = 0; t < 4; t++) {
      int ot = WV + 4 * t;
      f32x4 a = mfma16(wp2f[t][0], bf0.s8, (f32x4){0.f, 0.f, 0.f, 0.f});
      a = mfma16(wp2f[t][1], bf1.s8, a);
      int ob = ot * 16 + quad * 4;
      f32x4 bv = *(const f32x4*)&bp2g[ob];
      f32x4 res = a + bv;
      *(f32x4*)(OUT + (size_t)(e0g + ln15) * 256 + ob) = res;
    }
  }
}

// ---------------- main fused kernel ----------------
// 256 threads / 4 waves, dual 16-elem tiles per wave, TWO barriers total.
// LDS = 32768 (partials) + 6528 (xs) + 512 (sbias) = 39808 B.
__launch_bounds__(256, 2)
__global__ void gcn_main(const float* __restrict__ X,
                         const short* __restrict__ Mb2,
                         const short* __restrict__ Wp2p,
                         const short* __restrict__ W2p,
                         const short* __restrict__ W1b,
                         const float* __restrict__ bp1p,
                         const float* __restrict__ b2g,
                         const float* __restrict__ bp2g,
                         float* __restrict__ OUT) {
  __shared__ __align__(16) float pbuf[8192];   // 32768 B cross-wave partials
  __shared__ __align__(16) float xs[2 * 816];  // 6528 B input stage
  __shared__ __align__(16) float sbias[128];   // b2 | bp1p

  const int tid = threadIdx.x;
  const int wave = tid >> 6;
  const int lane = tid & 63;
  const int ln15 = lane & 15;
  const int quad = lane >> 4;
  const int bx = blockIdx.x;

  // ---- init ----
  for (int q = tid; q < 408; q += 256)
    ((f32x4*)xs)[q] = ((const f32x4*)(X + (size_t)bx * 1632))[q];
  short8 w1f[4];
#pragma unroll
  for (int ft = 0; ft < 4; ft++)
    w1f[ft] = *(const short8*)(W1b + (ft * 16 + ln15) * 8);
  if (tid < 128) sbias[tid] = (tid < 64) ? b2g[tid] : bp1p[tid - 64];
  __syncthreads();  // xs, sbias ready (barrier #1 of 2)

  if (wave == 0)
    waveBody<0>(Mb2, Wp2p, W2p, bp2g, OUT, pbuf, xs, sbias, w1f, bx, lane, ln15, quad);
  else if (wave == 1)
    waveBody<1>(Mb2, Wp2p, W2p, bp2g, OUT, pbuf, xs, sbias, w1f, bx, lane, ln15, quad);
  else if (wave == 2)
    waveBody<2>(Mb2, Wp2p, W2p, bp2g, OUT, pbuf, xs, sbias, w1f, bx, lane, ln15, quad);
  else
    waveBody<3>(Mb2, Wp2p, W2p, bp2g, OUT, pbuf, xs, sbias, w1f, bx, lane, ln15, quad);
}

extern "C" void kernel_launch(void* const* d_in, const int* in_sizes, int n_in,
                              void* d_out, int out_size, void* d_ws, size_t ws_size,
                              hipStream_t stream) {
  const float* X = (const float*)d_in[0];
  const float* W1 = (const float*)d_in[2];
  const float* b1 = (const float*)d_in[3];
  const float* W2 = (const float*)d_in[4];
  const float* b2 = (const float*)d_in[5];
  const float* W3 = (const float*)d_in[6];
  const float* b3 = (const float*)d_in[7];
  const float* Wp1 = (const float*)d_in[8];
  const float* bp1 = (const float*)d_in[9];
  const float* Wp2 = (const float*)d_in[10];
  const float* bp2 = (const float*)d_in[11];
  float* OUT = (float*)d_out;
  const int B = in_sizes[0] / 51;

  char* ws = (char*)d_ws;
  short* Mb = (short*)(ws + 0);          // 64*1088*2 = 139264 (k-permuted)
  short* Wp2b = (short*)(ws + 139264);   // 32768 (k-permuted)
  short* W2b = (short*)(ws + 172032);    // 8192 (k-permuted)
  short* W1b = (short*)(ws + 180224);    // 1024 (k=3 slot = b1)
  float* bp1p = (float*)(ws + 181248);   // 256

  prep<<<370, 256, 0, stream>>>(W1, W2, Wp2, W3, Wp1, b3, bp1, b1,
                                W1b, W2b, Wp2b, Mb, bp1p);
  gcn_main<<<B / 32, 256, 0, stream>>>(X, Mb, Wp2b, W2b, W1b, bp1p,
                                       b2, bp2, OUT);
}

// Round 11
// 143.360 us; speedup vs baseline: 1.3137x; 1.0296x over previous
//
#include <hip/hip_runtime.h>
#include <hip/hip_bf16.h>
#include <stdint.h>

typedef __attribute__((ext_vector_type(8))) short short8;
typedef __attribute__((ext_vector_type(4))) float f32x4;
typedef __attribute__((ext_vector_type(4))) unsigned int u32x4;
typedef __attribute__((ext_vector_type(2))) unsigned int u32x2;

// Skeleton (fixed in reference) — constexpr so fully-unrolled loops fold
// every index/degree/offset into immediates.
constexpr int kNBR[17][4] = {
    {7, 1, 4, 0}, {0, 2, 0, 0}, {1, 3, 0, 0}, {2, 0, 0, 0},
    {0, 5, 0, 0}, {4, 6, 0, 0}, {5, 0, 0, 0}, {0, 8, 0, 0},
    {7, 9, 11, 14}, {8, 10, 0, 0}, {9, 0, 0, 0}, {8, 12, 0, 0},
    {11, 13, 0, 0}, {12, 0, 0, 0}, {8, 15, 0, 0}, {14, 16, 0, 0},
    {15, 0, 0, 0}};
constexpr int kDEG[17] = {3,2,2,1,2,2,1,2,4,2,1,2,2,1,2,2,1};
constexpr float kRDEG[5] = {0.f, 1.f, 0.5f, 0.33333334f, 0.25f};
// per-wave output-joint tiles, balanced so sum(deg) = 8 per wave
constexpr int kWNT[4] = {3, 4, 5, 5};
constexpr int kWJT[4][5] = {{8, 1, 2, 0, 0},
                            {0, 4, 5, 3, 0},
                            {7, 9, 11, 6, 10},
                            {12, 14, 15, 13, 16}};
// packed per-joint neighbor float-offsets (nb*3 fits in a byte)
constexpr uint32_t kNBO(int i) {
  return (uint32_t)(kNBR[i][0] * 3) | ((uint32_t)(kNBR[i][1] * 3) << 8) |
         ((uint32_t)(kNBR[i][2] * 3) << 16) | ((uint32_t)(kNBR[i][3] * 3) << 24);
}

__device__ inline unsigned short f2bf(float f) {
  union { float f; uint32_t u; } v; v.f = f;
  uint32_t u = v.u;
  uint32_t r = u + 0x7fffu + ((u >> 16) & 1u);  // RNE
  return (unsigned short)(r >> 16);
}
// hardware v_cvt_pk_bf16_f32 (RNE), a in low 16, b in high 16
__device__ inline uint32_t pk2(float a, float b) {
  union { __hip_bfloat162 h; uint32_t u; } v;
  v.h = __float22bfloat162_rn(make_float2(a, b));
  return v.u;
}
__device__ inline f32x4 mfma16(short8 a, short8 b, f32x4 c) {
  return __builtin_amdgcn_mfma_f32_16x16x32_bf16(a, b, c, 0, 0, 0);
}

// ---------------- prep kernel ----------------
// R11: W1b becomes a 64x32 "K-replicated" layout: A[row][k] with
// k = 8q + c: c<3 -> W1[row][c] (same cols in every quad-slot group),
// k==3 -> b1[row] (quad0 only), else 0. The main kernel's L1 B-fragment
// places neighbor q's scaled features at k=8q..8q+2, so ONE MFMA computes
// W1 @ (w * sum_q x[nbr_q]) + b1 — the aggregation rides the K dimension.
// W2/Wp2/Mb keep the R9/R10 k-permutation (C-frag -> B-frag register reuse).
__global__ void prep(const float* __restrict__ W1,
                     const float* __restrict__ W2,
                     const float* __restrict__ Wp2,
                     const float* __restrict__ W3,
                     const float* __restrict__ Wp1,
                     const float* __restrict__ b3,
                     const float* __restrict__ bp1,
                     const float* __restrict__ b1,
                     short* __restrict__ W1b,
                     short* __restrict__ W2b,
                     short* __restrict__ Wp2b,
                     short* __restrict__ Mb,
                     float* __restrict__ bp1p) {
  __shared__ float w3s[4096];
  __shared__ float Qs[256];
  const int tid = threadIdx.x;
  const int bx = blockIdx.x;
  if (bx < 272) {
    for (int q = tid; q < 4096; q += 256) w3s[q] = W3[q];
    {
      int ro = tid >> 6, k = tid & 63;
      int r = bx * 4 + ro;
      int f = r / 17, i = r - f * 17;
      int dj = kDEG[i];
      float s = 0.f;
#pragma unroll
      for (int t = 0; t < 4; t++) {
        if (t < dj) {
          int nb = kNBR[i][t];
          s += kRDEG[kDEG[nb]] * Wp1[f * 1088 + nb * 64 + k];
        }
      }
      Qs[ro * 64 + k] = s;
    }
    __syncthreads();
    {
      int ro = tid >> 6, c = tid & 63;
      int r = bx * 4 + ro;
      int f = r / 17, i = r - f * 17;
      float s = 0.f;
#pragma unroll
      for (int k = 0; k < 64; k++) s += Qs[ro * 64 + k] * w3s[k * 64 + c];
      int h = c >> 5;
      int c5 = c & 31;
      int q = (c5 >> 2) & 3;
      int m = ((c5 >> 4) << 2) | (c5 & 3);
      int w = f >> 4, l15 = f & 15;
      Mb[((((w * 17 + i) * 2 + h) * 64) + q * 16 + l15) * 8 + m] = (short)f2bf(s);
    }
  } else if (bx < 360) {
    int q = (bx - 272) * 256 + tid;
    if (q < 4096) {  // W2 k-permuted
      int r = q >> 6, c = q & 63;
      int h = c >> 5, c5 = c & 31;
      int qq = (c5 >> 2) & 3, m = ((c5 >> 4) << 2) | (c5 & 3);
      W2b[r * 64 + h * 32 + qq * 8 + m] = (short)f2bf(W2[q]);
    }
    int q2 = q - 4096;
    if (q2 >= 0 && q2 < 16384) {  // Wp2 k-permuted
      int r = q2 >> 6, c = q2 & 63;
      int h = c >> 5, c5 = c & 31;
      int qq = (c5 >> 2) & 3, m = ((c5 >> 4) << 2) | (c5 & 3);
      Wp2b[r * 64 + h * 32 + qq * 8 + m] = (short)f2bf(Wp2[q2]);
    }
    int q3 = q - 20480;
    if (q3 >= 0 && q3 < 2048) {  // W1b 64x32 K-replicated
      int row = q3 >> 5, k = q3 & 31;
      int c = k & 7;
      short v = 0;
      if (c < 3) v = (short)f2bf(W1[row * 3 + c]);
      else if (k == 3) v = (short)f2bf(b1[row]);  // bias, quad0 slot only
      W1b[q3] = v;
    }
  } else {
    int wv = tid >> 6, l = tid & 63;
    int f = (bx - 360) * 4 + wv;
    float s = 0.f;
#pragma unroll
    for (int i = 0; i < 17; i++) s += Wp1[f * 1088 + i * 64 + l] * b3[l];
#pragma unroll
    for (int off = 32; off > 0; off >>= 1) s += __shfl_down(s, off);
    if (l == 0) bp1p[f] = bp1[f] + s;
  }
}

// ---------------- per-wave specialized body (R11) ----------------
// R10 structure (register-resident chain, 2 barriers) with two VALU fixes:
// (1) L1 neighbor aggregation moved into MFMA K-slots (all-lane fragment
//     build: quad q supplies neighbor q; no exec-masked quad0 serial sums);
// (2) packed activations stored as u32x4 quads written in place (no
//     register-concat v_movs feeding MFMA B-operands).
template <int WV>
__device__ __forceinline__ void waveBody(
    const short* __restrict__ Mb2, const short* __restrict__ Wp2p,
    const short* __restrict__ W2p, const float* __restrict__ bp2g,
    float* __restrict__ OUT, float* __restrict__ pbuf,
    float* __restrict__ xs, float* __restrict__ sbias,
    const short8 (&w1f)[4], int bx, int lane, int ln15, int quad) {
  constexpr int NT = kWNT[WV];
  const int xbase = ln15 * 51;
  const int q8 = quad * 8;
  const float bias1 = (quad == 0) ? 1.0f : 0.0f;

  short8 w2f[2][4];
#pragma unroll
  for (int h = 0; h < 2; h++)
#pragma unroll
    for (int ft = 0; ft < 4; ft++)
      w2f[h][ft] = *(const short8*)(W2p + (ft * 16 + ln15) * 64 + h * 32 + quad * 8);

  // ---- L1 (K-slot aggregation) + L2 (in-place packed quads) ----
  u32x4 pkh2q[2][NT][2];
#pragma unroll
  for (int t = 0; t < NT; t++) {
    const int j = kWJT[WV][t];
    const int dj = kDEG[j];
    const float wj = kRDEG[dj];
    u32x4 ph1q[4][2][2];  // [s][g][h], only [0..dj) used (static idx)
#pragma unroll
    for (int s = 0; s < 4; s++) {
      if (s < dj) {
        const int i = kNBR[j][s];
        const int di = kDEG[i];
        const float wi = kRDEG[di];
        // all-lane build: quad q supplies neighbor q of joint i, scaled;
        // unused quads (q >= di) contribute 0 via wq.
        const int off = (int)((kNBO(i) >> q8) & 0xffu);
        const int b = xbase + off;
        const float wq = (quad < di) ? wi : 0.f;
#pragma unroll
        for (int g = 0; g < 2; g++) {
          const float* xsg = xs + g * 816;
          union { short8 s8; u32x4 u; } fr;
          fr.u.x = pk2(xsg[b] * wq, xsg[b + 1] * wq);
          fr.u.y = pk2(xsg[b + 2] * wq, bias1);  // k=3 bias slot (quad0)
          fr.u.z = 0u;
          fr.u.w = 0u;
          f32x4 a[4];
#pragma unroll
          for (int ft = 0; ft < 4; ft++)
            a[ft] = mfma16(w1f[ft], fr.s8, (f32x4){0.f, 0.f, 0.f, 0.f});
          // relu+pack straight into u32x4 quads (B-frag layout, no movs)
          u32x4 q0, q1;
          q0.x = pk2(fmaxf(a[0].x, 0.f), fmaxf(a[0].y, 0.f));
          q0.y = pk2(fmaxf(a[0].z, 0.f), fmaxf(a[0].w, 0.f));
          q0.z = pk2(fmaxf(a[1].x, 0.f), fmaxf(a[1].y, 0.f));
          q0.w = pk2(fmaxf(a[1].z, 0.f), fmaxf(a[1].w, 0.f));
          q1.x = pk2(fmaxf(a[2].x, 0.f), fmaxf(a[2].y, 0.f));
          q1.y = pk2(fmaxf(a[2].z, 0.f), fmaxf(a[2].w, 0.f));
          q1.z = pk2(fmaxf(a[3].x, 0.f), fmaxf(a[3].y, 0.f));
          q1.w = pk2(fmaxf(a[3].z, 0.f), fmaxf(a[3].w, 0.f));
          ph1q[s][g][0] = q0;
          ph1q[s][g][1] = q1;
        }
      }
    }
#pragma unroll
    for (int g = 0; g < 2; g++) {
      f32x4 a[4];
#pragma unroll
      for (int ft = 0; ft < 4; ft++) a[ft] = (f32x4){0.f, 0.f, 0.f, 0.f};
#pragma unroll
      for (int s = 0; s < 4; s++)
        if (s < dj) {
#pragma unroll
          for (int h = 0; h < 2; h++) {
            union { u32x4 u; short8 s8; } bf;
            bf.u = ph1q[s][g][h];
#pragma unroll
            for (int ft = 0; ft < 4; ft++)
              a[ft] = mfma16(w2f[h][ft], bf.s8, a[ft]);
          }
        }
      u32x4 qq[2];
#pragma unroll
      for (int ft = 0; ft < 4; ft++) {
        int fb = ft * 16 + quad * 4;
        f32x4 bv = *(const f32x4*)&sbias[fb];
        uint32_t lo = pk2(fmaxf(a[ft].x * wj + bv.x, 0.f),
                          fmaxf(a[ft].y * wj + bv.y, 0.f));
        uint32_t hi = pk2(fmaxf(a[ft].z * wj + bv.z, 0.f),
                          fmaxf(a[ft].w * wj + bv.w, 0.f));
        if (ft & 1) { qq[ft >> 1].z = lo; qq[ft >> 1].w = hi; }
        else        { qq[ft >> 1].x = lo; qq[ft >> 1].y = hi; }
      }
      pkh2q[g][t][0] = qq[0];
      pkh2q[g][t][1] = qq[1];
    }
  }

  // ---- Pool-partial: B = pkh2q (direct), A streamed from Mb2 ----
  f32x4 zacc[4][2];
#pragma unroll
  for (int w4 = 0; w4 < 4; w4++) {
    zacc[w4][0] = (f32x4){0.f, 0.f, 0.f, 0.f};
    zacc[w4][1] = (f32x4){0.f, 0.f, 0.f, 0.f};
  }
  const short8* mb = (const short8*)Mb2;
#pragma unroll
  for (int t = 0; t < NT; t++) {
    const int i = kWJT[WV][t];
#pragma unroll
    for (int h = 0; h < 2; h++) {
      union { u32x4 u; short8 s8; } bf0, bf1;
      bf0.u = pkh2q[0][t][h];
      bf1.u = pkh2q[1][t][h];
#pragma unroll
      for (int w4 = 0; w4 < 4; w4++) {
        short8 af = mb[(((w4 * 17 + i) * 2 + h) * 64) + lane];
        zacc[w4][0] = mfma16(af, bf0.s8, zacc[w4][0]);
        zacc[w4][1] = mfma16(af, bf1.s8, zacc[w4][1]);
      }
    }
  }
  // ---- partial writeback (contiguous 1KB per slot, conflict-free) ----
#pragma unroll
  for (int w4 = 0; w4 < 4; w4++)
#pragma unroll
    for (int g = 0; g < 2; g++)
      *(f32x4*)(pbuf + WV * 2048 + (w4 * 2 + g) * 256 + lane * 4) = zacc[w4][g];
  // prefetch Wp2 fragments; latency hides behind the barrier
  short8 wp2f[4][2];
#pragma unroll
  for (int t = 0; t < 4; t++) {
    int ot = WV + 4 * t;
    wp2f[t][0] = *(const short8*)(Wp2p + (ot * 16 + ln15) * 64 + quad * 8);
    wp2f[t][1] = *(const short8*)(Wp2p + (ot * 16 + ln15) * 64 + 32 + quad * 8);
  }
  __syncthreads();  // partials ready (barrier #2 of 2)

  // ---- redundant full reduce: z packed in place (no zb exchange) ----
  u32x4 zpq[2][2];
#pragma unroll
  for (int w4 = 0; w4 < 4; w4++) {
    f32x4 bv = *(const f32x4*)&sbias[64 + w4 * 16 + quad * 4];
#pragma unroll
    for (int g = 0; g < 2; g++) {
      const int gw = w4 * 2 + g;
      f32x4 s0 = *(const f32x4*)(pbuf + 0 * 2048 + gw * 256 + lane * 4);
      f32x4 s1 = *(const f32x4*)(pbuf + 1 * 2048 + gw * 256 + lane * 4);
      f32x4 s2 = *(const f32x4*)(pbuf + 2 * 2048 + gw * 256 + lane * 4);
      f32x4 s3 = *(const f32x4*)(pbuf + 3 * 2048 + gw * 256 + lane * 4);
      f32x4 s = (s0 + s1) + (s2 + s3);
      uint32_t lo = pk2(fmaxf(s.x + bv.x, 0.f), fmaxf(s.y + bv.y, 0.f));
      uint32_t hi = pk2(fmaxf(s.z + bv.z, 0.f), fmaxf(s.w + bv.w, 0.f));
      if (w4 & 1) { zpq[g][w4 >> 1].z = lo; zpq[g][w4 >> 1].w = hi; }
      else        { zpq[g][w4 >> 1].x = lo; zpq[g][w4 >> 1].y = hi; }
    }
  }

  // ---- Pool layer 2: B = zpq (direct), k-permuted Wp2, both tiles ----
  const int e0 = bx * 32;
#pragma unroll
  for (int g = 0; g < 2; g++) {
    union { u32x4 u; short8 s8; } bf0, bf1;
    bf0.u = zpq[g][0];
    bf1.u = zpq[g][1];
    int e0g = e0 + g * 16;
#pragma unroll
    for (int t = 0; t < 4; t++) {
      int ot = WV + 4 * t;
      f32x4 a = mfma16(wp2f[t][0], bf0.s8, (f32x4){0.f, 0.f, 0.f, 0.f});
      a = mfma16(wp2f[t][1], bf1.s8, a);
      int ob = ot * 16 + quad * 4;
      f32x4 bv = *(const f32x4*)&bp2g[ob];
      f32x4 res = a + bv;
      *(f32x4*)(OUT + (size_t)(e0g + ln15) * 256 + ob) = res;
    }
  }
}

// ---------------- main fused kernel ----------------
// 256 threads / 4 waves, dual 16-elem tiles per wave, TWO barriers total.
// LDS = 32768 (partials) + 6528 (xs) + 512 (sbias) = 39808 B.
__launch_bounds__(256, 2)
__global__ void gcn_main(const float* __restrict__ X,
                         const short* __restrict__ Mb2,
                         const short* __restrict__ Wp2p,
                         const short* __restrict__ W2p,
                         const short* __restrict__ W1b,
                         const float* __restrict__ bp1p,
                         const float* __restrict__ b2g,
                         const float* __restrict__ bp2g,
                         float* __restrict__ OUT) {
  __shared__ __align__(16) float pbuf[8192];   // 32768 B cross-wave partials
  __shared__ __align__(16) float xs[2 * 816];  // 6528 B input stage
  __shared__ __align__(16) float sbias[128];   // b2 | bp1p

  const int tid = threadIdx.x;
  const int wave = tid >> 6;
  const int lane = tid & 63;
  const int ln15 = lane & 15;
  const int quad = lane >> 4;
  const int bx = blockIdx.x;

  // ---- init ----
  for (int q = tid; q < 408; q += 256)
    ((f32x4*)xs)[q] = ((const f32x4*)(X + (size_t)bx * 1632))[q];
  short8 w1f[4];
#pragma unroll
  for (int ft = 0; ft < 4; ft++)
    w1f[ft] = *(const short8*)(W1b + (ft * 16 + (lane & 15)) * 32 + (lane >> 4) * 8);
  if (tid < 128) sbias[tid] = (tid < 64) ? b2g[tid] : bp1p[tid - 64];
  __syncthreads();  // xs, sbias ready (barrier #1 of 2)

  if (wave == 0)
    waveBody<0>(Mb2, Wp2p, W2p, bp2g, OUT, pbuf, xs, sbias, w1f, bx, lane, ln15, quad);
  else if (wave == 1)
    waveBody<1>(Mb2, Wp2p, W2p, bp2g, OUT, pbuf, xs, sbias, w1f, bx, lane, ln15, quad);
  else if (wave == 2)
    waveBody<2>(Mb2, Wp2p, W2p, bp2g, OUT, pbuf, xs, sbias, w1f, bx, lane, ln15, quad);
  else
    waveBody<3>(Mb2, Wp2p, W2p, bp2g, OUT, pbuf, xs, sbias, w1f, bx, lane, ln15, quad);
}

extern "C" void kernel_launch(void* const* d_in, const int* in_sizes, int n_in,
                              void* d_out, int out_size, void* d_ws, size_t ws_size,
                              hipStream_t stream) {
  const float* X = (const float*)d_in[0];
  const float* W1 = (const float*)d_in[2];
  const float* b1 = (const float*)d_in[3];
  const float* W2 = (const float*)d_in[4];
  const float* b2 = (const float*)d_in[5];
  const float* W3 = (const float*)d_in[6];
  const float* b3 = (const float*)d_in[7];
  const float* Wp1 = (const float*)d_in[8];
  const float* bp1 = (const float*)d_in[9];
  const float* Wp2 = (const float*)d_in[10];
  const float* bp2 = (const float*)d_in[11];
  float* OUT = (float*)d_out;
  const int B = in_sizes[0] / 51;

  char* ws = (char*)d_ws;
  short* Mb = (short*)(ws + 0);          // 64*1088*2 = 139264 (k-permuted)
  short* Wp2b = (short*)(ws + 139264);   // 32768 (k-permuted)
  short* W2b = (short*)(ws + 172032);    // 8192 (k-permuted)
  short* W1b = (short*)(ws + 180224);    // 4096 (64x32 K-replicated, +b1)
  float* bp1p = (float*)(ws + 184320);   // 256

  prep<<<376, 256, 0, stream>>>(W1, W2, Wp2, W3, Wp1, b3, bp1, b1,
                                W1b, W2b, Wp2b, Mb, bp1p);
  gcn_main<<<B / 32, 256, 0, stream>>>(X, Mb, Wp2b, W2b, W1b, bp1p,
                                       b2, bp2, OUT);
}